// Round 7
// baseline (135.313 us; speedup 1.0000x reference)
//
#include <hip/hip_runtime.h>
#include <hip/hip_bf16.h>

namespace {
constexpr int AH = 9, AW = 9, NS = AH * AW;   // 81 samples per ROI
constexpr int C = 256, H = 64, W = 64, HW = H * W;
constexpr float SCALE = 0.0625f;
constexpr int ELEMS = C * NS;                 // 20736 outputs per ROI
constexpr int SPW = 11;                       // samples per wave (4*11 >= 41)
constexpr int SH0 = 41;                       // samples in s-half 0 (half 1: 40)
}

__device__ __forceinline__ float bf_up(unsigned u) { return __uint_as_float(u << 16); }

// ---------- pass 1: NCHW f32 -> NHWC bf16 into workspace ----------
__global__ __launch_bounds__(256)
void nchw_to_nhwc_bf16_kernel(const float* __restrict__ in,
                              ushort* __restrict__ out)
{
    __shared__ float tile[64][33];
    const int b  = blockIdx.z;
    const int p0 = blockIdx.x * 32;
    const int c0 = blockIdx.y * 64;
    const float* src = in + (size_t)b * C * HW;
    ushort*      dst = out + (size_t)b * HW * C;
    const int tx = threadIdx.x;   // 0..31
    const int ty = threadIdx.y;   // 0..7
    #pragma unroll
    for (int k = 0; k < 8; ++k)
        tile[ty + 8 * k][tx] = src[(size_t)(c0 + ty + 8 * k) * HW + p0 + tx];
    __syncthreads();
    #pragma unroll
    for (int k = 0; k < 4; ++k) {
        const int p = ty + 8 * k;             // 0..31
        __hip_bfloat16 lo = __float2bfloat16(tile[2 * tx][p]);
        __hip_bfloat16 hi = __float2bfloat16(tile[2 * tx + 1][p]);
        ushort2 u;
        u.x = *reinterpret_cast<ushort*>(&lo);
        u.y = *reinterpret_cast<ushort*>(&hi);
        *reinterpret_cast<ushort2*>(dst + (size_t)(p0 + p) * C + c0 + 2 * tx) = u;
    }
}

// ---------- pass 2: ROI align, one block per (ROI, 64ch quarter, s-half) ----
// lane owns 1 channel (ushort per corner); wave w owns samples soff+11w..
__global__ __launch_bounds__(256, 8)
void rod_align_q_kernel(const ushort* __restrict__ nhwc,
                        const float* __restrict__ rois,
                        float* __restrict__ out)
{
    __shared__ float4 s_w[NS];
    __shared__ int    s_o[NS];                // (y0*W + x0) * C   (ushort units)
    __shared__ float  s_buf[SH0][65];         // [sample within half][channel]

    const int r    = blockIdx.x >> 3;
    const int q    = (blockIdx.x >> 1) & 3;   // 64-channel quarter
    const int sh   = blockIdx.x & 1;          // sample half
    const int t    = threadIdx.x;
    const int wave = t >> 6;
    const int lane = t & 63;

    const int soff   = sh ? SH0 : 0;
    const int scount = sh ? (NS - SH0) : SH0; // 40 : 41
    const int slast  = soff + scount - 1;

    const float* roi = rois + r * 5;
    const int   b  = (int)roi[0];
    const float x1 = roi[1] * SCALE;
    const float y1 = roi[2] * SCALE;
    const float x2 = roi[3] * SCALE;
    const float y2 = roi[4] * SCALE;
    const float bin_h = (y2 - y1) * 0.125f;
    const float bin_w = (x2 - x1) * 0.125f;

    if (t < NS) {
        const int i = t / AW;
        const int j = t - i * AW;
        const float Y = y1 + (float)i * bin_h;
        const float X = x1 + (float)j * bin_w;
        const bool valid = (Y >= 0.f) && (Y < (float)H) &&
                           (X >= 0.f) && (X < (float)W);
        const float fy = fminf(fmaxf(floorf(Y), 0.f), (float)(H - 2));
        const float fx = fminf(fmaxf(floorf(X), 0.f), (float)(W - 2));
        const float ly = Y - fy, lx = X - fx;
        const float hy = 1.f - ly, hx = 1.f - lx;
        const float v = valid ? 1.f : 0.f;
        s_o[t] = ((int)fy * W + (int)fx) * C;
        s_w[t] = make_float4(hy * hx * v, hy * lx * v, ly * hx * v, ly * lx * v);
    }
    __syncthreads();

    // ushort view: 1 bf16 channel per lane; quarter selects channels 64q..64q+63
    const ushort* __restrict__ pe =
        nhwc + (size_t)b * (HW * C) + q * 64 + lane;
    float* __restrict__ ob = out + (size_t)r * ELEMS;

    const int s0 = soff + wave * SPW;
    float acc[SPW];

    #pragma unroll
    for (int i = 0; i < SPW; ++i) {
        int s = s0 + i; if (s > slast) s = slast;     // tail: benign repeats
        const int o = s_o[s];
        const ushort q00 = pe[o];
        const ushort q01 = pe[o + C];          // x+1
        const ushort q10 = pe[o + W * C];      // y+1
        const ushort q11 = pe[o + W * C + C];
        const float4 w4 = s_w[s];
        acc[i] = bf_up(q00) * w4.x + bf_up(q01) * w4.y
               + bf_up(q10) * w4.z + bf_up(q11) * w4.w;
    }

    // full-wave LDS fill: s_buf[row][lane], bank-stride 1, conflict-free
    #pragma unroll
    for (int i = 0; i < SPW; ++i) {
        int s = s0 + i; if (s > slast) s = slast;
        s_buf[s - soff][lane] = acc[i];
    }
    __syncthreads();

    // store: 64ch x scount floats; out[r, 64q+cc, soff+ssx], f = cc*scount+ssx
    float* __restrict__ oc = ob + (q * 64) * NS + soff;
    const int total = 64 * scount;
    int cc  = t / scount;
    int ssx = t - cc * scount;
    const int dcc  = (scount == SH0) ? 6 : 6;             // 256 = 6*41+10 = 6*40+16
    const int dssx = 256 - dcc * scount;                  // 10 or 16
    for (int f = t; f < total; f += 256) {
        __builtin_nontemporal_store(s_buf[ssx][cc], &oc[cc * NS + ssx]);
        cc += dcc; ssx += dssx;
        if (ssx >= scount) { ssx -= scount; ++cc; }
    }
}

// ---------- fallback: direct NCHW f32 ----------
__global__ __launch_bounds__(256, 8)
void rod_align_nchw_kernel(const float* __restrict__ feat,
                           const float* __restrict__ rois,
                           float* __restrict__ out)
{
    __shared__ float4 s_w[NS];
    __shared__ int    s_off[NS];

    const int r = blockIdx.x;
    const int t = threadIdx.x;

    const float* roi = rois + r * 5;
    const int   b  = (int)roi[0];
    const float x1 = roi[1] * SCALE;
    const float y1 = roi[2] * SCALE;
    const float x2 = roi[3] * SCALE;
    const float y2 = roi[4] * SCALE;
    const float bin_h = (y2 - y1) * 0.125f;
    const float bin_w = (x2 - x1) * 0.125f;

    if (t < NS) {
        const int i = t / AW;
        const int j = t - i * AW;
        const float Y = y1 + (float)i * bin_h;
        const float X = x1 + (float)j * bin_w;
        const bool valid = (Y >= 0.f) && (Y < (float)H) &&
                           (X >= 0.f) && (X < (float)W);
        const float fy = fminf(fmaxf(floorf(Y), 0.f), (float)(H - 2));
        const float fx = fminf(fmaxf(floorf(X), 0.f), (float)(W - 2));
        const float ly = Y - fy, lx = X - fx;
        const float hy = 1.f - ly, hx = 1.f - lx;
        const float v = valid ? 1.f : 0.f;
        s_off[t] = (int)fy * W + (int)fx;
        s_w[t] = make_float4(hy * hx * v, hy * lx * v, ly * hx * v, ly * lx * v);
    }
    __syncthreads();

    const float* __restrict__ fb = feat + (size_t)b * (C * HW);
    float* __restrict__ ob = out + (size_t)r * ELEMS;

    int c = t / NS;
    int s = t - c * NS;
    #pragma unroll 3
    for (int it = 0; it < NS; ++it) {
        const int off = (c << 12) + s_off[s];
        const float4 w = s_w[s];
        const float f00 = fb[off];
        const float f01 = fb[off + 1];
        const float f10 = fb[off + W];
        const float f11 = fb[off + W + 1];
        ob[t + (it << 8)] = f00 * w.x + f01 * w.y + f10 * w.z + f11 * w.w;
        c += 3; s += 13;
        if (s >= NS) { s -= NS; ++c; }
    }
}

extern "C" void kernel_launch(void* const* d_in, const int* in_sizes, int n_in,
                              void* d_out, int out_size, void* d_ws, size_t ws_size,
                              hipStream_t stream) {
    const float* feat = (const float*)d_in[0];
    const float* rois = (const float*)d_in[1];
    float* outp = (float*)d_out;
    const int R = in_sizes[1] / 5;            // 2048
    const int B = in_sizes[0] / (C * HW);     // 4

    const size_t nhwc_bytes = (size_t)B * HW * C * sizeof(ushort);

    if (ws_size >= nhwc_bytes) {
        ushort* nhwc = (ushort*)d_ws;
        dim3 tgrid(HW / 32, C / 64, B);
        dim3 tblk(32, 8);
        nchw_to_nhwc_bf16_kernel<<<tgrid, tblk, 0, stream>>>(feat, nhwc);
        rod_align_q_kernel<<<8 * R, 256, 0, stream>>>(nhwc, rois, outp);
    } else {
        rod_align_nchw_kernel<<<R, 256, 0, stream>>>(feat, rois, outp);
    }
}

// Round 8
// 47.877 us; speedup vs baseline: 2.8263x; 2.8263x over previous
//
#include <hip/hip_runtime.h>
#include <hip/hip_bf16.h>

namespace {
constexpr int AH = 9, AW = 9, NS = AH * AW;   // 81 samples per ROI
constexpr int C = 256, H = 64, W = 64, HW = H * W;
constexpr float SCALE = 0.0625f;
constexpr int ELEMS = C * NS;                 // 20736 outputs per ROI
constexpr int SPW = 11;                       // samples per wave (8*11 >= 81)
}

__device__ __forceinline__ float bf_lo(unsigned u) { return __uint_as_float(u << 16); }
__device__ __forceinline__ float bf_hi(unsigned u) { return __uint_as_float(u & 0xffff0000u); }

// ---------- pass 1: NCHW f32 -> NHWC bf16 into workspace ----------
__global__ __launch_bounds__(256)
void nchw_to_nhwc_bf16_kernel(const float* __restrict__ in,
                              ushort* __restrict__ out)
{
    __shared__ float tile[64][33];
    const int b  = blockIdx.z;
    const int p0 = blockIdx.x * 32;
    const int c0 = blockIdx.y * 64;
    const float* src = in + (size_t)b * C * HW;
    ushort*      dst = out + (size_t)b * HW * C;
    const int tx = threadIdx.x;   // 0..31
    const int ty = threadIdx.y;   // 0..7
    #pragma unroll
    for (int k = 0; k < 8; ++k)
        tile[ty + 8 * k][tx] = src[(size_t)(c0 + ty + 8 * k) * HW + p0 + tx];
    __syncthreads();
    #pragma unroll
    for (int k = 0; k < 4; ++k) {
        const int p = ty + 8 * k;             // 0..31
        __hip_bfloat16 lo = __float2bfloat16(tile[2 * tx][p]);
        __hip_bfloat16 hi = __float2bfloat16(tile[2 * tx + 1][p]);
        ushort2 u;
        u.x = *reinterpret_cast<ushort*>(&lo);
        u.y = *reinterpret_cast<ushort*>(&hi);
        *reinterpret_cast<ushort2*>(dst + (size_t)(p0 + p) * C + c0 + 2 * tx) = u;
    }
}

// ---------- pass 2: ROI align, 512-thread block per (ROI, 128-ch half) ------
// 8 waves; wave owns 11 samples; lane owns 2 channels (dword gathers).
// acc[11][2] = 22 VGPR -> fits 64-VGPR cap of (512,8) => 32 waves/CU.
__global__ __launch_bounds__(512, 8)
void rod_align_half8_kernel(const ushort* __restrict__ nhwc,
                            const float* __restrict__ rois,
                            float* __restrict__ out)
{
    __shared__ float4 s_w[NS];
    __shared__ int    s_o[NS];                // (y0*W + x0) * C/2  (dword units)
    __shared__ float  s_buf[NS][65];

    const int r    = blockIdx.x >> 1;
    const int half = blockIdx.x & 1;
    const int t    = threadIdx.x;
    const int wave = t >> 6;                  // 0..7
    const int lane = t & 63;

    const float* roi = rois + r * 5;
    const int   b  = (int)roi[0];
    const float x1 = roi[1] * SCALE;
    const float y1 = roi[2] * SCALE;
    const float x2 = roi[3] * SCALE;
    const float y2 = roi[4] * SCALE;
    const float bin_h = (y2 - y1) * 0.125f;
    const float bin_w = (x2 - x1) * 0.125f;

    if (t < NS) {
        const int i = t / AW;
        const int j = t - i * AW;
        const float Y = y1 + (float)i * bin_h;
        const float X = x1 + (float)j * bin_w;
        const bool valid = (Y >= 0.f) && (Y < (float)H) &&
                           (X >= 0.f) && (X < (float)W);
        const float fy = fminf(fmaxf(floorf(Y), 0.f), (float)(H - 2));
        const float fx = fminf(fmaxf(floorf(X), 0.f), (float)(W - 2));
        const float ly = Y - fy, lx = X - fx;
        const float hy = 1.f - ly, hx = 1.f - lx;
        const float v = valid ? 1.f : 0.f;
        s_o[t] = ((int)fy * W + (int)fx) * (C / 2);
        s_w[t] = make_float4(hy * hx * v, hy * lx * v, ly * hx * v, ly * lx * v);
    }
    __syncthreads();

    // dword view: 2 bf16 channels per lane; half selects channels 128*half..+127
    const unsigned* __restrict__ pd =
        reinterpret_cast<const unsigned*>(nhwc + (size_t)b * (HW * C)) + half * 64 + lane;
    float* __restrict__ ob = out + (size_t)r * ELEMS;

    const int s0 = wave * SPW;
    float acc[SPW][2];

    #pragma unroll
    for (int i = 0; i < SPW; ++i) {
        int s = s0 + i; if (s > NS - 1) s = NS - 1;   // wave-7 tail: benign repeats
        const int o = s_o[s];
        const unsigned q00 = pd[o];
        const unsigned q01 = pd[o + 128];      // x+1:  +C/2 dwords
        const unsigned q10 = pd[o + 8192];     // y+1:  +W*C/2 dwords
        const unsigned q11 = pd[o + 8320];
        const float4 w4 = s_w[s];
        acc[i][0] = bf_lo(q00) * w4.x + bf_lo(q01) * w4.y
                  + bf_lo(q10) * w4.z + bf_lo(q11) * w4.w;
        acc[i][1] = bf_hi(q00) * w4.x + bf_hi(q01) * w4.y
                  + bf_hi(q10) * w4.z + bf_hi(q11) * w4.w;
    }

    // 2 rounds: channels 64g..64g+63 (of this half) held by lanes 32g..32g+31
    #pragma unroll 1
    for (int g = 0; g < 2; ++g) {
        __syncthreads();                      // s_buf free (prev round consumed)
        if ((lane >> 5) == g) {
            const int kk = (lane & 31) * 2;
            #pragma unroll
            for (int i = 0; i < SPW; ++i) {
                int s = s0 + i; if (s > NS - 1) s = NS - 1;
                s_buf[s][kk]     = acc[i][0];
                s_buf[s][kk + 1] = acc[i][1];
            }
        }
        __syncthreads();
        // contiguous 5184-dword slab: out[r, 128*half + 64g + cc, ss]
        float* __restrict__ oc = ob + (half * 128 + g * 64) * NS;
        for (int f = t; f < 64 * NS; f += 512) {
            const int cc  = f / NS;
            const int ssx = f - cc * NS;
            __builtin_nontemporal_store(s_buf[ssx][cc], &oc[f]);
        }
    }
}

// ---------- fallback: direct NCHW f32 ----------
__global__ __launch_bounds__(256, 8)
void rod_align_nchw_kernel(const float* __restrict__ feat,
                           const float* __restrict__ rois,
                           float* __restrict__ out)
{
    __shared__ float4 s_w[NS];
    __shared__ int    s_off[NS];

    const int r = blockIdx.x;
    const int t = threadIdx.x;

    const float* roi = rois + r * 5;
    const int   b  = (int)roi[0];
    const float x1 = roi[1] * SCALE;
    const float y1 = roi[2] * SCALE;
    const float x2 = roi[3] * SCALE;
    const float y2 = roi[4] * SCALE;
    const float bin_h = (y2 - y1) * 0.125f;
    const float bin_w = (x2 - x1) * 0.125f;

    if (t < NS) {
        const int i = t / AW;
        const int j = t - i * AW;
        const float Y = y1 + (float)i * bin_h;
        const float X = x1 + (float)j * bin_w;
        const bool valid = (Y >= 0.f) && (Y < (float)H) &&
                           (X >= 0.f) && (X < (float)W);
        const float fy = fminf(fmaxf(floorf(Y), 0.f), (float)(H - 2));
        const float fx = fminf(fmaxf(floorf(X), 0.f), (float)(W - 2));
        const float ly = Y - fy, lx = X - fx;
        const float hy = 1.f - ly, hx = 1.f - lx;
        const float v = valid ? 1.f : 0.f;
        s_off[t] = (int)fy * W + (int)fx;
        s_w[t] = make_float4(hy * hx * v, hy * lx * v, ly * hx * v, ly * lx * v);
    }
    __syncthreads();

    const float* __restrict__ fb = feat + (size_t)b * (C * HW);
    float* __restrict__ ob = out + (size_t)r * ELEMS;

    int c = t / NS;
    int s = t - c * NS;
    #pragma unroll 3
    for (int it = 0; it < NS; ++it) {
        const int off = (c << 12) + s_off[s];
        const float4 w = s_w[s];
        const float f00 = fb[off];
        const float f01 = fb[off + 1];
        const float f10 = fb[off + W];
        const float f11 = fb[off + W + 1];
        ob[t + (it << 8)] = f00 * w.x + f01 * w.y + f10 * w.z + f11 * w.w;
        c += 3; s += 13;
        if (s >= NS) { s -= NS; ++c; }
    }
}

extern "C" void kernel_launch(void* const* d_in, const int* in_sizes, int n_in,
                              void* d_out, int out_size, void* d_ws, size_t ws_size,
                              hipStream_t stream) {
    const float* feat = (const float*)d_in[0];
    const float* rois = (const float*)d_in[1];
    float* outp = (float*)d_out;
    const int R = in_sizes[1] / 5;            // 2048
    const int B = in_sizes[0] / (C * HW);     // 4

    const size_t nhwc_bytes = (size_t)B * HW * C * sizeof(ushort);

    if (ws_size >= nhwc_bytes) {
        ushort* nhwc = (ushort*)d_ws;
        dim3 tgrid(HW / 32, C / 64, B);
        dim3 tblk(32, 8);
        nchw_to_nhwc_bf16_kernel<<<tgrid, tblk, 0, stream>>>(feat, nhwc);
        rod_align_half8_kernel<<<2 * R, 512, 0, stream>>>(nhwc, rois, outp);
    } else {
        rod_align_nchw_kernel<<<R, 256, 0, stream>>>(feat, rois, outp);
    }
}